// Round 10
// baseline (131.955 us; speedup 1.0000x reference)
//
#include <hip/hip_runtime.h>

#define NLAT 361
#define NLON 720
#define NF   361            // MMAX = rfft bins kept
#define NCH  32
#define NCK  (NCH * NLAT)   // 11552
#define KP   384            // stage2 K padded (per channel)
#define KD   768            // stage1 DFT K padded (n samples)
#define MD   384            // stage1 DFT M padded (f)
#define AROW 392            // stage2 LDS row stride for A (16B-unit stride 49: conflict-free)
#define BROW 72             // stage1 LDS row stride (f16)
#define WBROW 40            // stage2 per-wave W chunk LDS row stride (f16): 80B

typedef _Float16 h16;
typedef _Float16 f16x4 __attribute__((ext_vector_type(4)));
typedef _Float16 f16x8 __attribute__((ext_vector_type(8)));
typedef float    f32x4 __attribute__((ext_vector_type(4)));

#define PLANE ((size_t)NF * NCH * KP)   // f16 elements per (re|im) plane

// Build padded f16 DFT matrices directly (scale folded in).
__global__ __launch_bounds__(256) void k_build_T(
    h16* __restrict__ Tre, h16* __restrict__ Tim) {
    int idx = blockIdx.x * 256 + threadIdx.x;
    if (idx >= MD * KD) return;
    int f = idx / KD, n = idx - f * KD;
    float re = 0.f, im = 0.f;
    if (f < NF && n < NLON) {
        int j = (f * n) % NLON;
        float ang = -6.283185307179586f * ((float)j / (float)NLON);
        float s, c;
        sincosf(ang, &s, &c);
        const float scale = 6.283185307179586f / (float)NLON;
        re = c * scale; im = s * scale;
    }
    Tre[idx] = (h16)re;
    Tim[idx] = (h16)im;
}

// Stage 1 (MFMA): xf[pl][f][c][klat] = sum_n T[pl][f][n] * x[c,klat][n]
__global__ __launch_bounds__(256) void k_stage1m(
    const float* __restrict__ x, const h16* __restrict__ Tre,
    const h16* __restrict__ Tim, h16* __restrict__ xfh) {
    __shared__ h16 As[2][64][BROW];
    __shared__ h16 Bs[64][BROW];
    const int t    = threadIdx.x;
    const int f0   = blockIdx.x * 64;
    const int n0   = blockIdx.y * 64;
    const int lane = t & 63, wv = t >> 6;
    const int wm   = wv & 1, wn = wv >> 1;
    const int col  = lane & 15, kq = lane >> 4;

    f32x4 acc[2][2][2];
    #pragma unroll
    for (int p = 0; p < 2; ++p)
        #pragma unroll
        for (int a = 0; a < 2; ++a)
            #pragma unroll
            for (int b = 0; b < 2; ++b) acc[p][a][b] = (f32x4)0.0f;

    for (int ks = 0; ks < 12; ++ks) {
        __syncthreads();
        #pragma unroll
        for (int i = 0; i < 4; ++i) {
            int task = t + i * 256;
            int pl   = task >> 9;
            int rem  = task & 511;
            int r    = rem >> 3, ch = rem & 7;
            const h16* Tp = pl ? Tim : Tre;
            f16x8 v = *(const f16x8*)&Tp[(size_t)(f0 + r) * KD + ks * 64 + ch * 8];
            *(f16x8*)&As[pl][r][ch * 8] = v;
        }
        #pragma unroll
        for (int p = 0; p < 4; ++p) {
            int r = p * 16 + (t >> 4), c4 = t & 15;
            int rowg = n0 + r;
            int n = ks * 64 + c4 * 4;
            float4 v = make_float4(0.f, 0.f, 0.f, 0.f);
            if (rowg < NCK && n < NLON)
                v = *(const float4*)&x[(size_t)rowg * NLON + n];
            f16x4 h = { (h16)v.x, (h16)v.y, (h16)v.z, (h16)v.w };
            *(f16x4*)&Bs[r][c4 * 4] = h;
        }
        __syncthreads();
        #pragma unroll
        for (int kk = 0; kk < 2; ++kk) {
            f16x8 bfr[2], afr[2][2];
            #pragma unroll
            for (int nt = 0; nt < 2; ++nt)
                bfr[nt] = *(const f16x8*)&Bs[wn * 32 + nt * 16 + col][kk * 32 + kq * 8];
            #pragma unroll
            for (int pl = 0; pl < 2; ++pl)
                #pragma unroll
                for (int mt = 0; mt < 2; ++mt)
                    afr[pl][mt] = *(const f16x8*)&As[pl][wm * 32 + mt * 16 + col][kk * 32 + kq * 8];
            #pragma unroll
            for (int pl = 0; pl < 2; ++pl)
                #pragma unroll
                for (int mt = 0; mt < 2; ++mt)
                    #pragma unroll
                    for (int nt = 0; nt < 2; ++nt)
                        acc[pl][mt][nt] = __builtin_amdgcn_mfma_f32_16x16x32_f16(
                            afr[pl][mt], bfr[nt], acc[pl][mt][nt], 0, 0, 0);
        }
    }

    #pragma unroll
    for (int nt = 0; nt < 2; ++nt) {
        int rowg = n0 + wn * 32 + nt * 16 + col;
        if (rowg >= NCK) continue;
        int c    = rowg / NLAT;
        int klat = rowg - c * NLAT;
        size_t cbase = (size_t)c * KP + klat;
        #pragma unroll
        for (int pl = 0; pl < 2; ++pl)
            #pragma unroll
            for (int mt = 0; mt < 2; ++mt)
                #pragma unroll
                for (int r = 0; r < 4; ++r) {
                    int f = f0 + wm * 32 + mt * 16 + kq * 4 + r;
                    if (f < NF)
                        xfh[(size_t)pl * PLANE + (size_t)f * NCH * KP + cbase] =
                            (h16)acc[pl][mt][nt][r];
                }
    }
}

// Stage 2 (MFMA): outws[m][c][l] = sum_k xf[m][c][k] * W[m][l][k]  (re,im)
// Grid (361, 3), 512 thr. Wave owns ONE l-tile (16 rows x full K).
// W is staged per-wave through PRIVATE LDS (no block barrier needed):
//   load chunk = 16 rows x 32 k, 8 coalesced instrs (2 whole rows each,
//   128B contiguous per half-wave) -> cvt f16 -> ds_write -> ds_read_b128
//   in exact MFMA B-fragment order. 3-deep register rotation bounds
//   in-flight chunks (and VGPRs). K-loop remains barrier-free.
__global__ __launch_bounds__(512, 4) void k_stage2(
    const h16* __restrict__ xfh, const float* __restrict__ W,
    float2* __restrict__ outws) {
    __shared__ h16 Ah[2 * NCH * AROW];       // 50,176 B
    __shared__ h16 Wb[8][2][16 * WBROW];     // 20,480 B  (per-wave dbuf)
    const int m     = blockIdx.x;
    const int t     = threadIdx.x;
    const int lane  = t & 63;
    const int wv    = t >> 6;                 // 0..7
    const int lt    = blockIdx.y * 8 + wv;    // 0..23 (23 = fully OOB, discarded)
    const int col   = lane & 15;
    const int krow  = lane >> 4;              // 0..3
    const int krow8 = krow * 8;
    const int klane = lane & 31;
    const int half  = lane >> 5;              // 0/1

    const float* Wm = W + (size_t)m * NLAT * NLAT;

    // per-i row pointers for chunk loads: instr i covers rows 2i, 2i+1
    const float* rowp[8];
    #pragma unroll
    for (int i = 0; i < 8; ++i) {
        int l  = lt * 16 + 2 * i + half;
        int lc = (l < NLAT) ? l : (NLAT - 1);   // clamp: clamped cols are never stored
        rowp[i] = Wm + (size_t)lc * NLAT + klane;
    }
    h16* wb0 = &Wb[wv][0][0];
    h16* wb1 = &Wb[wv][1][0];

    float r0[8], r1[8], r2[8];
    // chunk c: k-range [c*32, c*32+32); k>=361 overruns into next W row
    // (garbage x A-pad-zero = 0); <=88B past W end on last row of last m.
#define LOADC(c, R) { _Pragma("unroll") \
    for (int i = 0; i < 8; ++i) (R)[i] = rowp[i][(c) * 32]; }
#define CVTW(c, R) { h16* wbb = ((c) & 1) ? wb1 : wb0; _Pragma("unroll") \
    for (int i = 0; i < 8; ++i) wbb[(2 * i + half) * WBROW + klane] = (h16)(R)[i]; }

    LOADC(0, r0); LOADC(1, r1); LOADC(2, r2);

    // stage A once (block-shared): 2 planes x 32 c x 48 16B-chunks.
    // Chunks covering klat>360 zero-filled (replaces global memset).
    #pragma unroll
    for (int i = 0; i < 6; ++i) {
        int task = t + i * 512;
        int ri   = task / 1536;
        int rem  = task - ri * 1536;
        int c    = rem / 48, k8 = rem - c * 48;
        f16x8 v;
        if (k8 < 46) {
            v = *(const f16x8*)&xfh[(size_t)ri * PLANE + ((size_t)(m * NCH + c)) * KP + k8 * 8];
        } else {
            #pragma unroll
            for (int e = 0; e < 8; ++e) v[e] = (h16)0.f;
        }
        if (k8 == 45) {
            #pragma unroll
            for (int e = 1; e < 8; ++e) v[e] = (h16)0.f;   // klat 361..367
        }
        *(f16x8*)&Ah[(ri * NCH + c) * AROW + k8 * 8] = v;
    }

    CVTW(0, r0);   // waits only chunk-0 loads; 1,2 stay in flight

    f32x4 acc[2][2];   // [ct][plane]
    #pragma unroll
    for (int ct = 0; ct < 2; ++ct)
        #pragma unroll
        for (int pl = 0; pl < 2; ++pl)
            acc[ct][pl] = (f32x4)0.0f;

    __syncthreads();   // Ah visible; the ONLY barrier

    #pragma unroll
    for (int ks = 0; ks < 12; ++ks) {
        // issue chunk ks+3 into the register slot freed by chunk ks
        if (ks + 3 < 12) {
            if ((ks % 3) == 0)      { LOADC(ks + 3, r0); }
            else if ((ks % 3) == 1) { LOADC(ks + 3, r1); }
            else                    { LOADC(ks + 3, r2); }
        }

        const h16* wbr = (ks & 1) ? wb1 : wb0;
        f16x8 bf = *(const f16x8*)&wbr[col * WBROW + krow8];

        f16x8 af[2][2];
        #pragma unroll
        for (int pl = 0; pl < 2; ++pl)
            #pragma unroll
            for (int ct = 0; ct < 2; ++ct)
                af[pl][ct] = *(const f16x8*)&Ah[(pl * NCH + ct * 16 + col) * AROW + ks * 32 + krow8];

        #pragma unroll
        for (int ct = 0; ct < 2; ++ct)
            #pragma unroll
            for (int pl = 0; pl < 2; ++pl)
                acc[ct][pl] = __builtin_amdgcn_mfma_f32_16x16x32_f16(
                    af[pl][ct], bf, acc[ct][pl], 0, 0, 0);

        // convert+write chunk ks+1 into the other buffer (per-wave, no barrier)
        if (ks < 11) {
            int c = ks + 1;
            if ((c % 3) == 0)      { CVTW(c, r0); }
            else if ((c % 3) == 1) { CVTW(c, r1); }
            else                   { CVTW(c, r2); }
        }
    }
#undef LOADC
#undef CVTW

    // epilogue: D col(l)=lane&15, row(c)=(lane>>4)*4+reg
    const int l = lt * 16 + col;
    if (l < NLAT) {
        #pragma unroll
        for (int ct = 0; ct < 2; ++ct) {
            #pragma unroll
            for (int r = 0; r < 4; ++r) {
                int c = ct * 16 + krow * 4 + r;
                outws[((size_t)m * NCH + c) * NLAT + l] =
                    make_float2(acc[ct][0][r], acc[ct][1][r]);
            }
        }
    }
}

// Transpose: out[cl][m] = ws[m][cl]   (float2 elements), 361 x 11552
__global__ __launch_bounds__(256) void k_transpose(
    const float2* __restrict__ src, float2* __restrict__ dst) {
    __shared__ float2 tile[32][33];
    const int tx = threadIdx.x & 31, ty = threadIdx.x >> 5;
    const int cl0 = blockIdx.x * 32, m0 = blockIdx.y * 32;
    #pragma unroll
    for (int i = 0; i < 4; ++i) {
        int mm = m0 + ty + i * 8;
        if (mm < NLAT) tile[ty + i * 8][tx] = src[(size_t)mm * NCK + cl0 + tx];
    }
    __syncthreads();
    #pragma unroll
    for (int i = 0; i < 4; ++i) {
        int mm = m0 + tx;
        int cl = cl0 + ty + i * 8;
        if (mm < NLAT) dst[(size_t)cl * NLAT + mm] = tile[tx][ty + i * 8];
    }
}

extern "C" void kernel_launch(void* const* d_in, const int* in_sizes, int n_in,
                              void* d_out, int out_size, void* d_ws, size_t ws_size,
                              hipStream_t stream) {
    const float* x = (const float*)d_in[0];
    const float* W = (const float*)d_in[1];
    float2* out2 = (float2*)d_out;

    char* ws = (char*)d_ws;
    h16*    Tre   = (h16*)(ws + 8192);
    h16*    Tim   = (h16*)(ws + 8192 + 589824);
    h16*    xfh   = (h16*)(ws + 1187840);
    float2* outws = (float2*)(ws + 1187840 + 2 * PLANE * sizeof(h16));

    k_build_T<<<(MD * KD + 255) / 256, 256, 0, stream>>>(Tre, Tim);
    k_stage1m<<<dim3(6, 181), 256, 0, stream>>>(x, Tre, Tim, xfh);
    k_stage2<<<dim3(NF, 3), 512, 0, stream>>>(xfh, W, outws);
    k_transpose<<<dim3(361, 12), 256, 0, stream>>>(outws, out2);
}

// Round 11
// 100.276 us; speedup vs baseline: 1.3159x; 1.3159x over previous
//
#include <hip/hip_runtime.h>

#define NLAT 361
#define NLON 720
#define NF   361            // MMAX = rfft bins kept
#define NCH  32
#define NCK  (NCH * NLAT)   // 11552
#define KP   384            // stage2 K padded (per channel)
#define KD   768            // stage1 DFT K padded (n samples)
#define MD   384            // stage1 DFT M padded (f)
#define AROW 392            // stage2 LDS row stride for A (16B-unit stride 49: conflict-free)
#define BROW 72             // stage1 LDS row stride (f16)

typedef _Float16 h16;
typedef _Float16 f16x4 __attribute__((ext_vector_type(4)));
typedef _Float16 f16x8 __attribute__((ext_vector_type(8)));
typedef float    f32x4 __attribute__((ext_vector_type(4)));

#define PLANE ((size_t)NF * NCH * KP)   // f16 elements per (re|im) plane

// Build padded f16 DFT matrices directly (scale folded in).
__global__ __launch_bounds__(256) void k_build_T(
    h16* __restrict__ Tre, h16* __restrict__ Tim) {
    int idx = blockIdx.x * 256 + threadIdx.x;
    if (idx >= MD * KD) return;
    int f = idx / KD, n = idx - f * KD;
    float re = 0.f, im = 0.f;
    if (f < NF && n < NLON) {
        int j = (f * n) % NLON;
        float ang = -6.283185307179586f * ((float)j / (float)NLON);
        float s, c;
        sincosf(ang, &s, &c);
        const float scale = 6.283185307179586f / (float)NLON;
        re = c * scale; im = s * scale;
    }
    Tre[idx] = (h16)re;
    Tim[idx] = (h16)im;
}

// Stage 1 (MFMA): xf[pl][f][c][klat] = sum_n T[pl][f][n] * x[c,klat][n]
__global__ __launch_bounds__(256) void k_stage1m(
    const float* __restrict__ x, const h16* __restrict__ Tre,
    const h16* __restrict__ Tim, h16* __restrict__ xfh) {
    __shared__ h16 As[2][64][BROW];
    __shared__ h16 Bs[64][BROW];
    const int t    = threadIdx.x;
    const int f0   = blockIdx.x * 64;
    const int n0   = blockIdx.y * 64;
    const int lane = t & 63, wv = t >> 6;
    const int wm   = wv & 1, wn = wv >> 1;
    const int col  = lane & 15, kq = lane >> 4;

    f32x4 acc[2][2][2];
    #pragma unroll
    for (int p = 0; p < 2; ++p)
        #pragma unroll
        for (int a = 0; a < 2; ++a)
            #pragma unroll
            for (int b = 0; b < 2; ++b) acc[p][a][b] = (f32x4)0.0f;

    for (int ks = 0; ks < 12; ++ks) {
        __syncthreads();
        #pragma unroll
        for (int i = 0; i < 4; ++i) {
            int task = t + i * 256;
            int pl   = task >> 9;
            int rem  = task & 511;
            int r    = rem >> 3, ch = rem & 7;
            const h16* Tp = pl ? Tim : Tre;
            f16x8 v = *(const f16x8*)&Tp[(size_t)(f0 + r) * KD + ks * 64 + ch * 8];
            *(f16x8*)&As[pl][r][ch * 8] = v;
        }
        #pragma unroll
        for (int p = 0; p < 4; ++p) {
            int r = p * 16 + (t >> 4), c4 = t & 15;
            int rowg = n0 + r;
            int n = ks * 64 + c4 * 4;
            float4 v = make_float4(0.f, 0.f, 0.f, 0.f);
            if (rowg < NCK && n < NLON)
                v = *(const float4*)&x[(size_t)rowg * NLON + n];
            f16x4 h = { (h16)v.x, (h16)v.y, (h16)v.z, (h16)v.w };
            *(f16x4*)&Bs[r][c4 * 4] = h;
        }
        __syncthreads();
        #pragma unroll
        for (int kk = 0; kk < 2; ++kk) {
            f16x8 bfr[2], afr[2][2];
            #pragma unroll
            for (int nt = 0; nt < 2; ++nt)
                bfr[nt] = *(const f16x8*)&Bs[wn * 32 + nt * 16 + col][kk * 32 + kq * 8];
            #pragma unroll
            for (int pl = 0; pl < 2; ++pl)
                #pragma unroll
                for (int mt = 0; mt < 2; ++mt)
                    afr[pl][mt] = *(const f16x8*)&As[pl][wm * 32 + mt * 16 + col][kk * 32 + kq * 8];
            #pragma unroll
            for (int pl = 0; pl < 2; ++pl)
                #pragma unroll
                for (int mt = 0; mt < 2; ++mt)
                    #pragma unroll
                    for (int nt = 0; nt < 2; ++nt)
                        acc[pl][mt][nt] = __builtin_amdgcn_mfma_f32_16x16x32_f16(
                            afr[pl][mt], bfr[nt], acc[pl][mt][nt], 0, 0, 0);
        }
    }

    #pragma unroll
    for (int nt = 0; nt < 2; ++nt) {
        int rowg = n0 + wn * 32 + nt * 16 + col;
        if (rowg >= NCK) continue;
        int c    = rowg / NLAT;
        int klat = rowg - c * NLAT;
        size_t cbase = (size_t)c * KP + klat;
        #pragma unroll
        for (int pl = 0; pl < 2; ++pl)
            #pragma unroll
            for (int mt = 0; mt < 2; ++mt)
                #pragma unroll
                for (int r = 0; r < 4; ++r) {
                    int f = f0 + wm * 32 + mt * 16 + kq * 4 + r;
                    if (f < NF)
                        xfh[(size_t)pl * PLANE + (size_t)f * NCH * KP + cbase] =
                            (h16)acc[pl][mt][nt][r];
                }
    }
}

// Stage 2 (MFMA): outws[m][c][l] = sum_k xf[m][c][k] * W[m][l][k]  (re,im)
// W[m][l][k] == 0 for l < m (Legendre triangle) -> only tiles lt >= m>>4
// are computed. Flat grid of 713 blocks: m<112 -> 3 groups, m<240 -> 2,
// else 1. Wave owns one l-tile: lt = (m>>4) + g*8 + wv, valid iff lt<=22.
// W streamed through a 6-chunk f32 register pipeline (2 ksteps each),
// converted to packed f16 as the next chunk flies. Barrier-free K-loop.
__global__ __launch_bounds__(512, 4) void k_stage2(
    const h16* __restrict__ xfh, const float* __restrict__ W,
    float2* __restrict__ outws) {
    __shared__ h16 Ah[2 * NCH * AROW];   // 50,176 B
    const int bid = blockIdx.x;
    int m, g;
    if (bid < 336)      { m = bid / 3;                g = bid - 3 * m; }
    else if (bid < 592) { int r = bid - 336; m = 112 + (r >> 1); g = r & 1; }
    else                { m = 240 + (bid - 592);      g = 0; }

    const int t     = threadIdx.x;
    const int lane  = t & 63;
    const int wv    = t >> 6;                   // 0..7
    const int lt    = (m >> 4) + g * 8 + wv;    // needed tiles start at m>>4
    const bool ok   = (lt <= 22);
    const int col   = lane & 15;
    const int krow  = lane >> 4;                // 0..3
    const int krow8 = krow * 8;

    const float* Wm = W + (size_t)m * NLAT * NLAT;
    const int l     = lt * 16 + col;
    const int lsafe = (l < NLAT) ? l : (NLAT - 1);
    const float* wrow = Wm + (size_t)lsafe * NLAT + krow8;

    // stage A first (its loads overlap the W pipeline's waits).
    // Chunks covering klat>360 are zero-filled (replaces global memset).
    #pragma unroll
    for (int i = 0; i < 6; ++i) {
        int task = t + i * 512;
        int ri   = task / 1536;
        int rem  = task - ri * 1536;
        int c    = rem / 48, k8 = rem - c * 48;
        f16x8 v;
        if (k8 < 46) {
            v = *(const f16x8*)&xfh[(size_t)ri * PLANE + ((size_t)(m * NCH + c)) * KP + k8 * 8];
        } else {
            #pragma unroll
            for (int e = 0; e < 8; ++e) v[e] = (h16)0.f;
        }
        if (k8 == 45) {
            #pragma unroll
            for (int e = 1; e < 8; ++e) v[e] = (h16)0.f;   // klat 361..367
        }
        *(f16x8*)&Ah[(ri * NCH + c) * AROW + k8 * 8] = v;
    }

    // W pipeline: 6 chunks x (2 ksteps x 8 dwords). wa/wb double-buffer.
    // Reads up to k=383 run into the next row (garbage x A-pad-zero = 0);
    // <=88B past W end on the very last row, within allocation slack.
    f16x8 wh[12];
    float wa[16], wb[16];
    if (ok) {
        #pragma unroll
        for (int e = 0; e < 16; ++e) wa[e] = wrow[(e >> 3) * 32 + (e & 7)];        // ks 0,1
        #pragma unroll
        for (int e = 0; e < 16; ++e) wb[e] = wrow[(2 + (e >> 3)) * 32 + (e & 7)];  // ks 2,3
    } else {
        #pragma unroll
        for (int e = 0; e < 16; ++e) { wa[e] = 0.f; wb[e] = 0.f; }
    }
    #pragma unroll
    for (int cc = 0; cc < 6; ++cc) {
        float* cur = (cc & 1) ? wb : wa;   // static after full unroll
        #pragma unroll
        for (int h = 0; h < 2; ++h)
            #pragma unroll
            for (int e = 0; e < 8; ++e)
                wh[cc * 2 + h][e] = (h16)cur[h * 8 + e];
        if (cc < 4 && ok) {
            #pragma unroll
            for (int e = 0; e < 16; ++e)
                cur[e] = wrow[((cc * 2 + 4) + (e >> 3)) * 32 + (e & 7)];
        }
    }

    f32x4 acc[2][2];   // [ct][plane]
    #pragma unroll
    for (int ct = 0; ct < 2; ++ct)
        #pragma unroll
        for (int pl = 0; pl < 2; ++pl)
            acc[ct][pl] = (f32x4)0.0f;

    __syncthreads();   // Ah visible; the ONLY barrier

    #pragma unroll
    for (int ks = 0; ks < 12; ++ks) {
        f16x8 af[2][2];
        #pragma unroll
        for (int pl = 0; pl < 2; ++pl)
            #pragma unroll
            for (int ct = 0; ct < 2; ++ct)
                af[pl][ct] = *(const f16x8*)&Ah[(pl * NCH + ct * 16 + col) * AROW + ks * 32 + krow8];

        #pragma unroll
        for (int ct = 0; ct < 2; ++ct)
            #pragma unroll
            for (int pl = 0; pl < 2; ++pl)
                acc[ct][pl] = __builtin_amdgcn_mfma_f32_16x16x32_f16(
                    af[pl][ct], wh[ks], acc[ct][pl], 0, 0, 0);
    }

    // epilogue: D col(l)=lane&15, row(c)=(lane>>4)*4+reg
    if (ok && l < NLAT) {
        #pragma unroll
        for (int ct = 0; ct < 2; ++ct) {
            #pragma unroll
            for (int r = 0; r < 4; ++r) {
                int c = ct * 16 + krow * 4 + r;
                outws[((size_t)m * NCH + c) * NLAT + l] =
                    make_float2(acc[ct][0][r], acc[ct][1][r]);
            }
        }
    }
}

// Transpose: out[cl][m] = ws[m][cl]  (float2), 361 x 11552.
// out is exactly 0 for l < m (Legendre triangle) — write zeros there
// (stage2 never computes those tiles; their outws region is garbage).
__global__ __launch_bounds__(256) void k_transpose(
    const float2* __restrict__ src, float2* __restrict__ dst) {
    __shared__ float2 tile[32][33];
    const int tx = threadIdx.x & 31, ty = threadIdx.x >> 5;
    const int cl0 = blockIdx.x * 32, m0 = blockIdx.y * 32;
    #pragma unroll
    for (int i = 0; i < 4; ++i) {
        int mm = m0 + ty + i * 8;
        if (mm < NLAT) tile[ty + i * 8][tx] = src[(size_t)mm * NCK + cl0 + tx];
    }
    __syncthreads();
    #pragma unroll
    for (int i = 0; i < 4; ++i) {
        int mm = m0 + tx;
        int cl = cl0 + ty + i * 8;
        if (mm < NLAT) {
            int l = cl - (cl / NLAT) * NLAT;
            float2 v = (l < mm) ? make_float2(0.f, 0.f) : tile[tx][ty + i * 8];
            dst[(size_t)cl * NLAT + mm] = v;
        }
    }
}

extern "C" void kernel_launch(void* const* d_in, const int* in_sizes, int n_in,
                              void* d_out, int out_size, void* d_ws, size_t ws_size,
                              hipStream_t stream) {
    const float* x = (const float*)d_in[0];
    const float* W = (const float*)d_in[1];
    float2* out2 = (float2*)d_out;

    char* ws = (char*)d_ws;
    h16*    Tre   = (h16*)(ws + 8192);
    h16*    Tim   = (h16*)(ws + 8192 + 589824);
    h16*    xfh   = (h16*)(ws + 1187840);
    float2* outws = (float2*)(ws + 1187840 + 2 * PLANE * sizeof(h16));

    k_build_T<<<(MD * KD + 255) / 256, 256, 0, stream>>>(Tre, Tim);
    k_stage1m<<<dim3(6, 181), 256, 0, stream>>>(x, Tre, Tim, xfh);
    k_stage2<<<713, 512, 0, stream>>>(xfh, W, outws);
    k_transpose<<<dim3(361, 12), 256, 0, stream>>>(outws, out2);
}